// Round 16
// baseline (34.678 us; speedup 1.0000x reference)
//
#include <hip/hip_runtime.h>

#define NF    4
#define NCLS  4
#define PLO   256
#define PHI   16384
#define KN    9
#define W27   27
#define CPX   64              // pixels per block (half a 128-row)
#define TW    68              // tile cols j0-2 .. j0+65
#define TSL   340             // float2 slots per batch tile
#define XSL   80              // 4f x 2 cell-rows x 10 cell-cols
#define NB    16              // batches staged per round
#define TSTR  344             // float2 stride per tile (pad)
#define XSBASE (NB * TSTR * 2)         // float offset of xs area = 11008
#define ARENA_F (XSBASE + NB * XSL)    // 12288 floats = 49152 B (>= weights 27648 B)

__global__ __launch_bounds__(256) void rect_up_kernel(
    const float* __restrict__ x,         // (B, NF*PLO)
    const float* __restrict__ orog,      // (B, PHI, 2)
    const float* __restrict__ wmap,      // (NCLS, NF, PHI, KN, 3)
    const float* __restrict__ bias_low,  // (NCLS, NF, PLO)
    const float* __restrict__ bias_high, // (NCLS, NF, PHI)
    const float* __restrict__ bias_orog, // (NCLS, 2, PHI)
    const int*   __restrict__ cls_ids,   // (B,)
    const int*   __restrict__ nb,        // (PHI, KN)
    float* __restrict__ out)             // (B, NF, PHI)
{
    // phase 1: weight staging (27648 B); phase 2 (after unpack): NB tiles+xs
    __shared__ float arena[ARENA_F];

    const int bid   = blockIdx.x;
    const int cls   = bid & 3;
    const int chunk = bid >> 2;              // 0..255
    const int t     = threadIdx.x;
    const int px    = t & 63;
    const int f     = t >> 6;                // wave == feature
    const int p     = chunk * CPX + px;
    const int pi    = chunk >> 1;            // pixel row (uniform per block)
    const int j0    = (chunk & 1) * 64;
    const int pj    = j0 + px;

    // ---- (1) weight staging: wave f stages feature f's slice ------------
    {
        const float4* s4 = reinterpret_cast<const float4*>(
            wmap + ((size_t)(cls * NF + f) * PHI + chunk * CPX) * W27);
        float4* d4 = reinterpret_cast<float4*>(arena) + f * 432;
        #pragma unroll
        for (int i = 0; i < 7; ++i) {
            const int idx = px + i * 64;     // 432 float4 per feature
            if (idx < 432) d4[idx] = s4[idx];
        }
    }

    // ---- class membership (wave width == BSZ == 64) ---------------------
    const unsigned long long cmask = __ballot(cls_ids[px] == cls);
    if (cmask == 0ULL) return;               // block-uniform, pre-barrier

    // ---- batch-invariant geometry (R8-verbatim) -------------------------
    const int R0 = pi - 2, C0 = j0 - 2;
    const int CR0 = (pi - 2 < 0 ? 0 : pi - 2) >> 3;
    const int CR1 = (pi + 2 > 127 ? 127 : pi + 2) >> 3;
    const int XC0 = (j0 - 2 < 0 ? 0 : j0 - 2) >> 3;
    const int ccl0 = ((pj - 2 < 0 ? 0 : pj - 2) >> 3) - XC0;   // 0..8

    int ldsoff[KN], sel[KN];
    #pragma unroll
    for (int k = 0; k < KN; ++k) {
        const int n  = nb[p * KN + k];
        const int ni = n >> 7, nj = n & 127; // within [pi±2],[pj±2]
        ldsoff[k] = (ni - R0) * TW + (nj - C0);
        const int rr = ((ni >> 3) != CR0) ? 1 : 0;
        const int cc = ((nj >> 3) != (XC0 + ccl0)) ? 1 : 0;
        sel[k] = rr * 2 + cc;
    }

    // ---- stager roles: tile slots t and 256+t; xs slot t ----------------
    int gAoff, gBoff = 0;
    float boA0, boA1, boB0 = 0.f, boB1 = 0.f;
    {
        const int r = t / TW, c = t - (t / TW) * TW;            // slot t < 340
        int nr = R0 + r; nr = nr < 0 ? 0 : (nr > 127 ? 127 : nr);
        int nc = C0 + c; nc = nc < 0 ? 0 : (nc > 127 ? 127 : nc);
        const int ns = nr * 128 + nc;
        gAoff = ns * 8;
        boA0  = bias_orog[(cls * 2 + 0) * PHI + ns];
        boA1  = bias_orog[(cls * 2 + 1) * PHI + ns];
    }
    if (t < TSL - 256) {                                        // slot 256+t
        const int s = 256 + t;
        const int r = s / TW, c = s - (s / TW) * TW;
        int nr = R0 + r; nr = nr < 0 ? 0 : (nr > 127 ? 127 : nr);
        int nc = C0 + c; nc = nc < 0 ? 0 : (nc > 127 ? 127 : nc);
        const int ns = nr * 128 + nc;
        gBoff = ns * 8;
        boB0  = bias_orog[(cls * 2 + 0) * PHI + ns];
        boB1  = bias_orog[(cls * 2 + 1) * PHI + ns];
    }
    int xIdx = 0; float xbl = 0.f;
    if (t < XSL) {                           // xs: (ff,rr,cc) -> ff*20+rr*10+cc
        const int ff = t / 20, q = t - (t / 20) * 20;
        const int rr = q / 10, c2 = q - (q / 10) * 10;
        const int crow = rr ? CR1 : CR0;
        int col = XC0 + c2; col = col > 15 ? 15 : col;
        xIdx = ff * PLO + crow * 16 + col;
        xbl  = bias_low[cls * (NF * PLO) + xIdx];
    }

    const float accInit = bias_high[(cls * NF + f) * PHI + p];

    __syncthreads();                         // weights staged

    // ---- unpack my (px,f) weights + 9->4 y-weight collapse --------------
    float w1[KN], w2[KN], wcy[4] = {0.f, 0.f, 0.f, 0.f};
    #pragma unroll
    for (int k = 0; k < KN; ++k) {
        const int base = f * 1728 + px * W27 + 3 * k;
        const float w0 = arena[base];
        w1[k] = arena[base + 1];
        w2[k] = arena[base + 2];
        #pragma unroll
        for (int j = 0; j < 4; ++j)
            wcy[j] += (sel[k] == j) ? w0 : 0.f;   // static idx only
    }

    const char* orogc = (const char*)orog;

    // ---- outer rounds over the class's batches (usually one) ------------
    unsigned long long m = cmask;
    while (m) {
        // collect up to NB batch ids (uniform; static-indexed array)
        int rb[NB];
        #pragma unroll
        for (int i = 0; i < NB; ++i) {
            rb[i] = m ? (__ffsll(m) - 1) : -1;
            if (m) m &= m - 1;
        }

        // issue ALL staged batches' loads (one latency exposure total)
        float2 vA[NB], vB[NB]; float vX[NB];
        #pragma unroll
        for (int i = 0; i < NB; ++i) {
            if (rb[i] >= 0) {
                const char* ob = orogc + (size_t)rb[i] * (PHI * 8);
                vA[i] = *reinterpret_cast<const float2*>(ob + gAoff);
                if (t < TSL - 256)
                    vB[i] = *reinterpret_cast<const float2*>(ob + gBoff);
                if (t < XSL)
                    vX[i] = x[rb[i] * (NF * PLO) + xIdx];
            }
        }

        __syncthreads();                     // arena free (unpack/compute done)

        #pragma unroll
        for (int i = 0; i < NB; ++i) {
            if (rb[i] >= 0) {
                float2* tp = reinterpret_cast<float2*>(arena) + i * TSTR;
                tp[t] = make_float2(vA[i].x - boA0, vA[i].y - boA1);
                if (t < TSL - 256)
                    tp[256 + t] = make_float2(vB[i].x - boB0, vB[i].y - boB1);
                if (t < XSL)
                    arena[XSBASE + i * XSL + t] = vX[i] - xbl;
            }
        }
        __syncthreads();                     // all tiles resident

        // ---- compute: ZERO barriers, all data in LDS/regs ---------------
        const int xb0 = f * 20 + ccl0;
        #pragma unroll
        for (int i = 0; i < NB; ++i) {
            if (rb[i] < 0) break;            // uniform (packed tail)
            const float2* tp = reinterpret_cast<const float2*>(arena) + i * TSTR;
            const float*  xsp = arena + XSBASE + i * XSL;
            float acc = accInit
                + xsp[xb0]      * wcy[0]
                + xsp[xb0 + 1]  * wcy[1]
                + xsp[xb0 + 10] * wcy[2]
                + xsp[xb0 + 11] * wcy[3];
            #pragma unroll
            for (int k = 0; k < KN; ++k) {
                const float2 o = tp[ldsoff[k]];
                acc += o.x * w1[k] + o.y * w2[k];
            }
            out[((size_t)rb[i] * NF + f) * PHI + p] = acc;
        }
        // loop continues only if >NB batches of this class (rare)
    }
}

extern "C" void kernel_launch(void* const* d_in, const int* in_sizes, int n_in,
                              void* d_out, int out_size, void* d_ws, size_t ws_size,
                              hipStream_t stream) {
    const float* x         = (const float*)d_in[0];
    const float* orog      = (const float*)d_in[1];
    const float* wmap      = (const float*)d_in[2];
    const float* bias_low  = (const float*)d_in[3];
    const float* bias_high = (const float*)d_in[4];
    const float* bias_orog = (const float*)d_in[5];
    const int*   cls_ids   = (const int*)d_in[6];
    const int*   nb        = (const int*)d_in[7];
    float* out = (float*)d_out;

    // grid: NCLS x 256 chunks = 1024 blocks x 4 waves (wave = feature).
    // Weights fetched once chip-wide; all class batches staged, then
    // computed with zero barriers.
    dim3 grid(NCLS * (PHI / CPX));
    dim3 block(256);
    rect_up_kernel<<<grid, block, 0, stream>>>(
        x, orog, wmap, bias_low, bias_high, bias_orog, cls_ids, nb, out);
}

// Round 17
// 27.421 us; speedup vs baseline: 1.2647x; 1.2647x over previous
//
#include <hip/hip_runtime.h>

#define BSZ  64
#define NF   4
#define NCLS 4
#define PLO  256
#define PHI  16384
#define KN   9
#define W27  27
#define CPX  64               // pixels per block (one chunk)
#define XSL  80               // NF * 2 cell-rows * 10 cell-cols

// (256,1): allow the allocator up to the full VGPR file — the 4-feature
// weight state needs ~150 regs; any tighter cap spills into the loop (R13).
__global__ __launch_bounds__(256, 1) void rect_up_kernel(
    const float* __restrict__ x,         // (B, NF*PLO)
    const float* __restrict__ orog,      // (B, PHI, 2)
    const float* __restrict__ wmap,      // (NCLS, NF, PHI, KN, 3)
    const float* __restrict__ bias_low,  // (NCLS, NF, PLO)
    const float* __restrict__ bias_high, // (NCLS, NF, PHI)
    const float* __restrict__ bias_orog, // (NCLS, 2, PHI)
    const int*   __restrict__ cls_ids,   // (B,)
    const int*   __restrict__ nb,        // (PHI, KN)
    float* __restrict__ out)             // (B, NF, PHI)
{
    __shared__ float wst[NF * CPX * W27];    // 27648 B weight arena (shared)
    __shared__ float xsb[NF][2][XSL];        // per-wave x-slice dbuf (2560 B)

    const int bid   = blockIdx.x;
    const int cls   = bid & 3;
    const int chunk = bid >> 2;              // 0..255
    const int t     = threadIdx.x;
    const int wave  = t >> 6;                // wave w stages feature w's weights
    const int lane  = t & 63;
    const int p     = chunk * CPX + lane;
    const int pi    = chunk >> 1;            // pixel row (uniform per block)
    const int j0    = (chunk & 1) * 64;
    const int pj    = j0 + lane;

    // ---- (1) stage weights: wave w loads feature w's slice --------------
    {
        const float4* s4 = reinterpret_cast<const float4*>(
            wmap + ((size_t)(cls * NF + wave) * PHI + chunk * CPX) * W27);
        float4* d4 = reinterpret_cast<float4*>(wst + wave * (CPX * W27));
        #pragma unroll
        for (int i = 0; i < 7; ++i) {
            const int idx = lane + i * 64;   // 432 float4 per feature
            if (idx < (CPX * W27) / 4) d4[idx] = s4[idx];
        }
    }

    // ---- class membership (uniform across block) -------------------------
    const unsigned long long cmask = __ballot(cls_ids[lane] == cls);
    if (cmask == 0ULL) return;               // block-uniform exit (no barrier yet)

    // ---- batch scan: wave w takes every 4th matching batch ---------------
    unsigned long long m = cmask;
    int ord = 0;
    auto nextb = [&]() -> int {
        while (m) {
            const int bb = __ffsll(m) - 1;
            m &= m - 1;
            const bool take = (ord == wave);
            ord = (ord + 1) & 3;
            if (take) return bb;
        }
        return -1;
    };
    int b = nextb();                         // this wave's first batch (may be -1)

    // ---- batch-invariant geometry ----------------------------------------
    const int CR0 = (pi - 2 < 0 ? 0 : pi - 2) >> 3;
    const int CR1 = (pi + 2 > 127 ? 127 : pi + 2) >> 3;
    const int XC0 = (j0 - 2 < 0 ? 0 : j0 - 2) >> 3;
    const int ccl0 = ((pj - 2 < 0 ? 0 : pj - 2) >> 3) - XC0;   // 0..8

    int nbOff[KN], sel[KN];
    #pragma unroll
    for (int k = 0; k < KN; ++k) {
        const int n = nb[p * KN + k];
        nbOff[k] = n * 8;
        const int rr = (((n >> 7) >> 3) != CR0) ? 1 : 0;
        const int cc = (((n & 127) >> 3) != (XC0 + ccl0)) ? 1 : 0;
        sel[k] = rr * 2 + cc;
    }

    // ---- xs stager roles: slots lane and 64+lane (lane<16) ---------------
    int xIdx0, xIdx1 = 0; float xbl0, xbl1 = 0.f;
    {
        const int s = lane, ff = s / 20, q = s % 20, rr = q / 10, c2 = q % 10;
        const int crow = rr ? CR1 : CR0;
        int col = XC0 + c2; col = col > 15 ? 15 : col;
        xIdx0 = ff * PLO + crow * 16 + col;
        xbl0  = bias_low[cls * (NF * PLO) + xIdx0];
    }
    if (lane < XSL - 64) {
        const int s = 64 + lane, ff = s / 20, q = s % 20, rr = q / 10, c2 = q % 10;
        const int crow = rr ? CR1 : CR0;
        int col = XC0 + c2; col = col > 15 ? 15 : col;
        xIdx1 = ff * PLO + crow * 16 + col;
        xbl1  = bias_low[cls * (NF * PLO) + xIdx1];
    }

    // ---- first batch's loads (fly under the weight stream) ---------------
    float o0[KN], o1[KN], xv0 = 0.f, xv1 = 0.f;
    if (b >= 0) {
        const char* ob = (const char*)orog + (size_t)b * (PHI * 8);
        #pragma unroll
        for (int k = 0; k < KN; ++k) {
            const float2 v = *reinterpret_cast<const float2*>(ob + nbOff[k]);
            o0[k] = v.x; o1[k] = v.y;
        }
        xv0 = x[b * (NF * PLO) + xIdx0];
        if (lane < XSL - 64) xv1 = x[b * (NF * PLO) + xIdx1];
    }

    // ---- bias gathers (batch-invariant) ----------------------------------
    float yob0[KN], yob1[KN];
    #pragma unroll
    for (int k = 0; k < KN; ++k) {
        const int n = nbOff[k] >> 3;
        yob0[k] = bias_orog[(cls * 2 + 0) * PHI + n];
        yob1[k] = bias_orog[(cls * 2 + 1) * PHI + n];
    }
    float bh[NF];
    #pragma unroll
    for (int f = 0; f < NF; ++f)
        bh[f] = bias_high[(cls * NF + f) * PHI + p];

    __syncthreads();                         // the ONLY barrier
    if (b < 0) return;                       // wave-uniform, after barrier

    // ---- unpack all 4 features' weights + fold biases --------------------
    float w1[NF][KN], w2[NF][KN], wcy[NF][4], accInit[NF];
    #pragma unroll
    for (int f = 0; f < NF; ++f) {
        #pragma unroll
        for (int j = 0; j < 4; ++j) wcy[f][j] = 0.f;
        #pragma unroll
        for (int k = 0; k < KN; ++k) {
            const float w0 = wst[f * (CPX * W27) + lane * W27 + 3 * k];
            w1[f][k] = wst[f * (CPX * W27) + lane * W27 + 3 * k + 1];
            w2[f][k] = wst[f * (CPX * W27) + lane * W27 + 3 * k + 2];
            #pragma unroll
            for (int j = 0; j < 4; ++j)
                wcy[f][j] += (sel[k] == j) ? w0 : 0.f;   // static idx only
        }
        float a = bh[f];
        #pragma unroll
        for (int k = 0; k < KN; ++k)
            a -= yob0[k] * w1[f][k] + yob1[k] * w2[f][k];
        accInit[f] = a;
    }

    // ---- stage first xs (pre-biased) -------------------------------------
    xsb[wave][0][lane] = xv0 - xbl0;
    if (lane < XSL - 64) xsb[wave][0][64 + lane] = xv1 - xbl1;

    // ---- batch loop: R10-proven structure (deferred write, reg copies) ---
    int cur = 0;
    while (true) {
        const int bn = nextb();

        float n0[KN], n1[KN], nx0 = 0.f, nx1 = 0.f;
        if (bn >= 0) {                       // issue next batch's loads
            const char* ob = (const char*)orog + (size_t)bn * (PHI * 8);
            #pragma unroll
            for (int k = 0; k < KN; ++k) {
                const float2 v = *reinterpret_cast<const float2*>(ob + nbOff[k]);
                n0[k] = v.x; n1[k] = v.y;
            }
            nx0 = x[bn * (NF * PLO) + xIdx0];
            if (lane < XSL - 64) nx1 = x[bn * (NF * PLO) + xIdx1];
        }

        // compute current batch (4 features; weights in regs, xs in LDS)
        const float* xs = &xsb[wave][cur][0];
        #pragma unroll
        for (int f = 0; f < NF; ++f) {
            const int base0 = f * 20 + ccl0;
            float acc = accInit[f]
                + xs[base0]      * wcy[f][0]
                + xs[base0 + 1]  * wcy[f][1]
                + xs[base0 + 10] * wcy[f][2]
                + xs[base0 + 11] * wcy[f][3];
            #pragma unroll
            for (int k = 0; k < KN; ++k)
                acc += o0[k] * w1[f][k] + o1[k] * w2[f][k];
            out[((size_t)b * NF + f) * PHI + p] = acc;
        }

        if (bn < 0) break;

        // write NEXT batch's xs into the OTHER buffer (deferred one phase)
        xsb[wave][cur ^ 1][lane] = nx0 - xbl0;
        if (lane < XSL - 64) xsb[wave][cur ^ 1][64 + lane] = nx1 - xbl1;
        #pragma unroll
        for (int k = 0; k < KN; ++k) { o0[k] = n0[k]; o1[k] = n1[k]; }
        b = bn; cur ^= 1;
    }
}

extern "C" void kernel_launch(void* const* d_in, const int* in_sizes, int n_in,
                              void* d_out, int out_size, void* d_ws, size_t ws_size,
                              hipStream_t stream) {
    const float* x         = (const float*)d_in[0];
    const float* orog      = (const float*)d_in[1];
    const float* wmap      = (const float*)d_in[2];
    const float* bias_low  = (const float*)d_in[3];
    const float* bias_high = (const float*)d_in[4];
    const float* bias_orog = (const float*)d_in[5];
    const int*   cls_ids   = (const int*)d_in[6];
    const int*   nb        = (const int*)d_in[7];
    float* out = (float*)d_out;

    // grid: NCLS x 256 chunks = 1024 blocks x 4 waves;
    // weights fetched once per chunk; batches split across waves in-block.
    dim3 grid(NCLS * (PHI / CPX));
    dim3 block(256);
    rect_up_kernel<<<grid, block, 0, stream>>>(
        x, orog, wmap, bias_low, bias_high, bias_orog, cls_ids, nb, out);
}